// Round 14
// baseline (309.612 us; speedup 1.0000x reference)
//
#include <hip/hip_runtime.h>

// ---------------------------------------------------------------------------
// MultiHeadAttention forward, MI355X/gfx950.
// B=2, T=2048, D=2048, H=16, Dh=128. fp32 in/out, bf16 MFMA internally.
// Reference quirks (faithful): multiplicative tril mask (masked scores = 0,
// NOT -inf -> exp(0)=1 contributions over ALL 2048 cols), scale = 1/sqrt(T).
// Round 14: attn -> V-fragments loaded DIRECTLY from global (L2-resident,
// 4 bh/XCD) into double-buffered registers; V ds_reads + V staging removed
// from the LDS port (which the arithmetic shows is the attn bottleneck:
// ~1250 LDS-port cy vs ~155 MFMA cy/SIMD per block-tile). K stays in
// ring-3 LDS; exact vmcnt(2) pipeline. Everything else unchanged.
// ---------------------------------------------------------------------------

typedef __attribute__((ext_vector_type(4))) float  f32x4;
typedef __attribute__((ext_vector_type(8))) short  bf16x8;
typedef __attribute__((ext_vector_type(4))) unsigned short u16x4;

#define AS1 __attribute__((address_space(1)))
#define AS3 __attribute__((address_space(3)))

__device__ __forceinline__ void llds16(const void* g, void* l) {
  __builtin_amdgcn_global_load_lds((const AS1 void*)g, (AS3 void*)l, 16, 0, 0);
}

__device__ __forceinline__ unsigned short f2bf(float f) {   // RNE
  unsigned int u = __builtin_bit_cast(unsigned int, f);
  u += 0x7fffu + ((u >> 16) & 1u);
  return (unsigned short)(u >> 16);
}

__device__ __forceinline__ unsigned short f2bfru(float f) { // round-half-up
  return (unsigned short)((__builtin_bit_cast(unsigned int, f) + 0x8000u) >> 16);
}

__device__ __forceinline__ float bf2f(unsigned short u) {
  return __builtin_bit_cast(float, (unsigned int)u << 16);
}

// ---------------------------------------------------------------------------
// Prep: z = 0..3 -> weight transpose (W [2048][2048] fp32 -> Wt[n][k] bf16),
//       z = 4    -> cast x (fp32 -> bf16), 8 elements/thread.
// ---------------------------------------------------------------------------
__global__ __launch_bounds__(256) void prep_kernel(
    const float* __restrict__ x,
    const float* __restrict__ W0, const float* __restrict__ W1,
    const float* __restrict__ W2, const float* __restrict__ W3,
    unsigned short* __restrict__ Xb,
    unsigned short* __restrict__ T0, unsigned short* __restrict__ T1,
    unsigned short* __restrict__ T2, unsigned short* __restrict__ T3) {
  __shared__ float tile[32][33];
  const int z = blockIdx.z;
  const int tx = threadIdx.x;       // 0..31
  const int ty = threadIdx.y;       // 0..7
  if (z == 4) {
    int blk = blockIdx.y * 64 + blockIdx.x;     // 0..4095
    int t = (ty << 5) + tx;                     // 0..255
    int i = blk * 512 + t;                      // f32x4 index; 4096*512 total
#pragma unroll
    for (int c = 0; c < 2; ++c) {
      f32x4 v = ((const f32x4*)x)[i + (c << 8)];
      u16x4 o;
      o[0] = f2bf(v[0]); o[1] = f2bf(v[1]); o[2] = f2bf(v[2]); o[3] = f2bf(v[3]);
      ((u16x4*)Xb)[i + (c << 8)] = o;
    }
    return;
  }
  const float* W = (z == 0) ? W0 : (z == 1) ? W1 : (z == 2) ? W2 : W3;
  unsigned short* Wt = (z == 0) ? T0 : (z == 1) ? T1 : (z == 2) ? T2 : T3;
  const int bx = blockIdx.x << 5;   // k base
  const int by = blockIdx.y << 5;   // n base
#pragma unroll
  for (int r = ty; r < 32; r += 8)
    tile[r][tx] = W[(size_t)(bx + r) * 2048 + by + tx];
  __syncthreads();
#pragma unroll
  for (int r = ty; r < 32; r += 8)
    Wt[(size_t)(by + r) * 2048 + bx + tx] = f2bf(tile[tx][r]);
}

// ---------------------------------------------------------------------------
// Fused QKV projection GEMM (round-8 best). Ring-3 depth-2 prefetch.
// C[M=4096][N=6144] = X[M][K=2048] @ Wt[N][K]^T, Wt = [Wq^T|Wk^T|Wv^T].
// BM=128, BN=256, BK=64. 8 waves (2M x 4N), wave tile 64x64 (4mi x 4ni).
// LDS: 3 slots x (A 16KB + B 32KB) = 144KB. Per K-tile: [vmcnt(6) ->
// s_barrier] ; stage(kt+2) ; 2 x { read 8 frags, 16 MFMA } free-running.
// Rows 128B = 8 chunks of 16B, chunk swizzle c ^= row&7 both sides.
// Grid 768 flat = 3 exact CU rounds; 3 bn panels per XCD (3MB -> L2).
// ---------------------------------------------------------------------------
__global__ __launch_bounds__(512, 2) void gemm_qkv(const unsigned short* __restrict__ A,
                                                   const unsigned short* __restrict__ Bt,
                                                   unsigned short* __restrict__ Qb,
                                                   unsigned short* __restrict__ Kb,
                                                   unsigned short* __restrict__ Vt) {
  constexpr int SLOT = 49152;                 // A 16384 + B 32768
  __shared__ __align__(16) char smem[3 * SLOT];
  const int tid  = threadIdx.x;
  const int lane = tid & 63;
  const int w    = tid >> 6;          // 0..7
  const int wr   = w >> 2;            // m-half (0..1)
  const int wc   = w & 3;             // n-quarter (0..3)
  const int q16  = lane >> 4;
  const int l15  = lane & 15;
  const int f    = blockIdx.x;
  const int g    = f >> 3;                        // 0..95
  const int bn   = (f & 7) * 3 + (g % 3);         // 0..23
  const int bm   = g / 3;                         // 0..31

  const int srow = tid >> 3;                      // 0..63
  const int scl  = (tid & 7) ^ (srow & 7);
  const unsigned short* aS = A  + (size_t)((bm << 7) + srow) * 2048 + (scl << 3);
  const unsigned short* bS = Bt + (size_t)(bn * 256 + srow) * 2048 + (scl << 3);
  const int sdst = tid << 4;

  // ds_read: row = base + l15, chunk = (ks*4 + q16) ^ (l15&7)
  const int swzb = (q16 ^ (l15 & 7)) << 4;        // ks=1: ^ 64
  const int aRd  = ((wr << 6) + l15) << 7;        // + mi*2048

  f32x4 acc[4][4];
#pragma unroll
  for (int i = 0; i < 4; ++i)
#pragma unroll
    for (int j = 0; j < 4; ++j) acc[i][j] = (f32x4){0.f, 0.f, 0.f, 0.f};

  auto stageT = [&](int kt, char* sb) {
    const size_t ko = (size_t)kt << 6;            // k element offset
    llds16(aS + ko,               sb + sdst);
    llds16(aS + (64 * 2048) + ko, sb + 8192 + sdst);
#pragma unroll
    for (int r = 0; r < 4; ++r)
      llds16(bS + (size_t)r * (64 * 2048) + ko, sb + 16384 + (r << 13) + sdst);
  };

  auto computeT = [&](const char* base) {
#pragma unroll
    for (int ks = 0; ks < 2; ++ks) {
      const int sw = swzb ^ (ks << 6);
      bf16x8 af[4], bf[4];
#pragma unroll
      for (int mi = 0; mi < 4; ++mi)
        af[mi] = *(const bf16x8*)(base + aRd + (mi << 11) + sw);
#pragma unroll
      for (int ni = 0; ni < 4; ++ni)
        bf[ni] = *(const bf16x8*)(base + 16384 + (((wc << 6) + l15) << 7) + (ni << 11) + sw);
      __builtin_amdgcn_s_setprio(1);
#pragma unroll
      for (int mi = 0; mi < 4; ++mi)
#pragma unroll
        for (int ni = 0; ni < 4; ++ni)
          acc[mi][ni] = __builtin_amdgcn_mfma_f32_16x16x32_bf16(af[mi], bf[ni], acc[mi][ni], 0, 0, 0);
      __builtin_amdgcn_s_setprio(0);
    }
  };

  char* s0 = smem;
  char* s1 = smem + SLOT;
  char* s2 = smem + 2 * SLOT;

#define W6()  asm volatile("s_waitcnt vmcnt(6)" ::: "memory")
#define W0()  asm volatile("s_waitcnt vmcnt(0)" ::: "memory")
#define BAR() __builtin_amdgcn_s_barrier()

  stageT(0, s0); stageT(1, s1);
  W6(); BAR();
  stageT(2, s2);
  computeT(s0);
#pragma unroll 1
  for (int b = 1; b <= 25; b += 3) {
    W6(); BAR(); stageT(b + 2, s0); computeT(s1);
    W6(); BAR(); stageT(b + 3, s1); computeT(s2);
    W6(); BAR(); stageT(b + 4, s2); computeT(s0);
  }
  W6(); BAR(); stageT(30, s0); computeT(s1);
  W6(); BAR(); stageT(31, s1); computeT(s2);
  W6(); BAR(); computeT(s0);
  W0(); BAR(); computeT(s1);

#undef W6
#undef W0
#undef BAR

  // epilogue. C/D layout: col = lane&15, row = (lane>>4)*4 + reg  [m89]
  const float qscale = 0.02209708691207961f;   // 1/sqrt(2048)
  const int rb = q16 << 2;
#pragma unroll
  for (int mi = 0; mi < 4; ++mi) {
    int m0 = (bm << 7) + (wr << 6) + (mi << 4) + rb;
#pragma unroll
    for (int ni = 0; ni < 4; ++ni) {
      int gn = (bn << 8) + (wc << 6) + (ni << 4) + l15;
      int region = gn >> 11;                     // 0 Q, 1 K, 2 V
      int nloc = gn & 2047;
      if (region == 0) {
#pragma unroll
        for (int j = 0; j < 4; ++j)
          Qb[(size_t)(m0 + j) * 2048 + nloc] = f2bf(acc[mi][ni][j] * qscale);
      } else if (region == 1) {
#pragma unroll
        for (int j = 0; j < 4; ++j)
          Kb[(size_t)(m0 + j) * 2048 + nloc] = f2bf(acc[mi][ni][j]);
      } else {
        u16x4 pk;
#pragma unroll
        for (int j = 0; j < 4; ++j) pk[j] = f2bf(acc[mi][ni][j]);
        int b = m0 >> 11, t = m0 & 2047;
        *(u16x4*)(Vt + ((size_t)((b << 4) + (nloc >> 7)) * 128 + (nloc & 127)) * 2048 + t) = pk;
      }
    }
  }
}

// ---------------------------------------------------------------------------
// Wo GEMM (passing): C fp32 = A[M][K] @ Bt[N][K]^T. BM=128, BN=128,
// wave tile 64x64 (2Mx2N), 4 waves, BK=32, ring-3 LDS, grid 512.
// ---------------------------------------------------------------------------
__global__ __launch_bounds__(256, 2) void gemm_wo(const unsigned short* __restrict__ A,
                                                  const unsigned short* __restrict__ Bt,
                                                  float* __restrict__ Co) {
  constexpr int SLOT = 8192 + 8192;
  __shared__ __align__(16) char smem[3 * SLOT];

  const int tid  = threadIdx.x;
  const int lane = tid & 63;
  const int w    = tid >> 6;                        // 0..3
  const int q16  = lane >> 4;
  const int l15  = lane & 15;
  const int f    = blockIdx.x;
  const int g    = f >> 3;
  const int bn   = ((f & 7) << 1) + (g & 1);
  const int bm   = g >> 1;
  const int wmb  = (w >> 1) << 6;
  const int wnb  = (w & 1) << 6;

  f32x4 acc[4][4];
#pragma unroll
  for (int i = 0; i < 4; ++i)
#pragma unroll
    for (int j = 0; j < 4; ++j) acc[i][j] = (f32x4){0.f, 0.f, 0.f, 0.f};

  const int rowA = tid >> 2;
  const int chA  = tid & 3;
  auto stageT = [&](int t, char* sb) {
    const int k0 = t << 5;
#pragma unroll
    for (int r = 0; r < 2; ++r) {
      int row = (r << 6) + rowA;
      const unsigned short* src = A + (size_t)((bm << 7) + row) * 2048 + k0
                                    + ((chA ^ ((row >> 1) & 3)) << 3);
      llds16(src, sb + (r << 12) + (w << 10));
    }
#pragma unroll
    for (int r = 0; r < 2; ++r) {
      int row = (r << 6) + rowA;
      const unsigned short* src = Bt + (size_t)((bn << 7) + row) * 2048 + k0
                                     + ((chA ^ ((row >> 1) & 3)) << 3);
      llds16(src, sb + 8192 + (r << 12) + (w << 10));
    }
  };

  auto computeT = [&](const char* base) {
    bf16x8 af[4], bf[4];
#pragma unroll
    for (int mi = 0; mi < 4; ++mi) {
      int row = wmb + (mi << 4) + l15;
      af[mi] = *(const bf16x8*)(base + (row << 6) + ((q16 ^ ((row >> 1) & 3)) << 4));
    }
#pragma unroll
    for (int ni = 0; ni < 4; ++ni) {
      int row = wnb + (ni << 4) + l15;
      bf[ni] = *(const bf16x8*)(base + 8192 + (row << 6) + ((q16 ^ ((row >> 1) & 3)) << 4));
    }
    __builtin_amdgcn_s_setprio(1);
#pragma unroll
    for (int mi = 0; mi < 4; ++mi)
#pragma unroll
      for (int ni = 0; ni < 4; ++ni)
        acc[mi][ni] = __builtin_amdgcn_mfma_f32_16x16x32_bf16(af[mi], bf[ni], acc[mi][ni], 0, 0, 0);
    __builtin_amdgcn_s_setprio(0);
  };

  auto STEP = [&](int t, char* cbase, char* sbase) {
    asm volatile("s_waitcnt vmcnt(4)" ::: "memory");
    __builtin_amdgcn_s_barrier();
    stageT(t + 2, sbase);
    computeT(cbase);
  };

  char* s0 = smem;
  char* s1 = smem + SLOT;
  char* s2 = smem + 2 * SLOT;

  stageT(0, s0); stageT(1, s1);
#pragma unroll 1
  for (int t = 0; t < 60; t += 3) {
    STEP(t,     s0, s2);
    STEP(t + 1, s1, s0);
    STEP(t + 2, s2, s1);
  }
  STEP(60, s0, s2);
  STEP(61, s1, s0);
  asm volatile("s_waitcnt vmcnt(4)" ::: "memory");
  __builtin_amdgcn_s_barrier();
  computeT(s2);
  asm volatile("s_waitcnt vmcnt(0)" ::: "memory");
  __builtin_amdgcn_s_barrier();
  computeT(s0);

  const int rb = q16 << 2;
#pragma unroll
  for (int mi = 0; mi < 4; ++mi) {
    int m0 = (bm << 7) + wmb + (mi << 4) + rb;
#pragma unroll
    for (int ni = 0; ni < 4; ++ni) {
      int n = (bn << 7) + wnb + (ni << 4) + l15;
#pragma unroll
      for (int j = 0; j < 4; ++j)
        Co[(size_t)(m0 + j) * 2048 + n] = acc[mi][ni][j];
    }
  }
}

// ---------------------------------------------------------------------------
// V suffix sums at 32-row granularity.
// Suf[j][bh][d] = sum_{s >= 32j} V[b, s, h, d],  j in 0..64 (Suf[64] = 0).
// ---------------------------------------------------------------------------
__global__ __launch_bounds__(256) void vsuf_kernel(const unsigned short* __restrict__ Vt,
                                                   float* __restrict__ Suf) {
  const int row  = blockIdx.x * 4 + (threadIdx.x >> 6);  // 0..4095
  const int lane = threadIdx.x & 63;
  const unsigned short* vp = Vt + (size_t)row * 2048 + (lane << 5);
  float a = 0.f;
#pragma unroll
  for (int c = 0; c < 4; ++c) {
    bf16x8 v = *(const bf16x8*)(vp + (c << 3));
#pragma unroll
    for (int j = 0; j < 8; ++j) a += bf2f((unsigned short)v[j]);
  }
  float I = a;
#pragma unroll
  for (int off = 1; off < 64; off <<= 1) {
    float t = __shfl_down(I, off, 64);
    I += (lane + off < 64) ? t : 0.f;
  }
  Suf[(size_t)lane * 4096 + row] = I;
  if (lane == 0) Suf[(size_t)64 * 4096 + row] = 0.f;
}

// ---------------------------------------------------------------------------
// Fused attention, QBLK=32/wave, V DIRECT-FROM-GLOBAL (L2-resident).
// Block = 4 waves x 32 q-rows = 128-row strip. Grid 512 = 32 bh x 16 strips.
// Decode: xcd = f&7, bh = xcd*4 + ((f>>3)&3) -> 4 bh per XCD (K+V 4MB = L2);
// strip = (f>>5 < 8) ? 15-(f>>5) : (f>>5)-8  (big strips dispatched first).
// Q PRE-SCALED by 1/sqrt(T). K in ring-3 LDS (2 llds/wave/tile); V fragments
// global->reg double-buffered (8 x dwordx4/wave/tile, lane-contiguous 16B).
// Per tile: [loadV(t+1), stageK(t+2)] -> compute -> vmcnt(2) -> barrier
// (retires exactly K(t+1)+V(t+1); K(t+2) stays in flight). Mask only on
// the straddling tile (s0 == t0); s >= t0+32 via V-suffix sums (p == 1).
// ---------------------------------------------------------------------------
__global__ __launch_bounds__(256, 2) void attn_kernel(const unsigned short* __restrict__ Q,
                                                      const unsigned short* __restrict__ K,
                                                      const unsigned short* __restrict__ V,  // Vt layout
                                                      const float* __restrict__ Suf,
                                                      unsigned short* __restrict__ O) {
  __shared__ __align__(16) char smem[32768];  // 3 K slots x 8KB | P 4x2KB
  const int tid  = threadIdx.x;
  const int lane = tid & 63;
  const int w    = tid >> 6;
  const int q16  = lane >> 4;
  const int l15  = lane & 15;
  const int f    = blockIdx.x;
  const int bh   = ((f & 7) << 2) + ((f >> 3) & 3);
  const int fs   = f >> 5;                            // 0..15
  const int strip = (fs < 8) ? (15 - fs) : (fs - 8);
  const int b  = bh >> 4;
  const size_t qkbase = ((size_t)(b << 11)) * 2048 + ((size_t)(bh & 15) << 7);
  const int rb = q16 << 2;
  char* Psm = smem + 24576 + (w << 11);       // 2KB per wave

  const int numIter = 4 * strip + 4;          // even, >= 4
  const int t0 = (strip << 7) + (w << 5);     // wave's 32-row base (mult of 32)

  // V fragment source: lane reads Vt[bh*128 + l15 + 16*ni][s0 + 8*q16 .. +8]
  const unsigned short* vSrc = V + ((size_t)bh << 18) + (size_t)l15 * 2048 + (q16 << 3);

#define LOADV(S0_, D)  do {                                                  \
    _Pragma("unroll")                                                        \
    for (int ni = 0; ni < 8; ++ni)                                           \
      D[ni] = *(const bf16x8*)(vSrc + (size_t)ni * 32768 + (S0_));           \
  } while (0)

#define STAGEK(S0_, SB) do {                                                 \
    _Pragma("unroll")                                                        \
    for (int c = 0; c < 2; ++c) {                                            \
      int ch = (w << 1) + c;                                                 \
      int rowK = (ch << 2) + q16;                                            \
      int colbK = (l15 << 4) ^ ((rowK & 7) << 4);                            \
      llds16(K + qkbase + (size_t)((S0_) + rowK) * 2048 + (colbK >> 1),      \
             (SB) + (ch << 10));                                             \
    }                                                                        \
  } while (0)

  // Q fragments, both subtiles (rows t0.. and t0+16..)
  bf16x8 qf[4], qg[4];
  {
    const unsigned short* qp = Q + qkbase + (size_t)(t0 + l15) * 2048 + (q16 << 3);
#pragma unroll
    for (int kk = 0; kk < 4; ++kk) qf[kk] = *(const bf16x8*)(qp + (kk << 5));
    const unsigned short* qp2 = qp + (size_t)16 * 2048;
#pragma unroll
    for (int kk = 0; kk < 4; ++kk) qg[kk] = *(const bf16x8*)(qp2 + (kk << 5));
  }

  f32x4 oA[8], oB[8];
#pragma unroll
  for (int i = 0; i < 8; ++i) { oA[i] = (f32x4){0.f,0.f,0.f,0.f}; oB[i] = (f32x4){0.f,0.f,0.f,0.f}; }
  float ellA[4] = {0.f,0.f,0.f,0.f}, ellB[4] = {0.f,0.f,0.f,0.f};
  bf16x8 vA[8], vB[8];

  // one tile's work. KSLOT: LDS slot of tile T; KSTG: slot for tile T+2.
  // VUSE: V regs for tile T (loaded during T-1); VLD: dest for tile T+1.
#define TILE(T, KSLOT, KSTG, VUSE, VLD) do {                                 \
    const int s0_ = (T) << 5;                                                \
    const bool hasNext_  = ((T) + 1 < numIter);                              \
    const bool hasStage_ = ((T) + 2 < numIter);                              \
    if (hasNext_)  LOADV(s0_ + 32, VLD);                                     \
    if (hasStage_) STAGEK(s0_ + 64, KSTG);                                   \
    if (s0_ <= t0) {                                                         \
      const char* kb_ = (KSLOT);                                             \
      f32x4 sA = (f32x4){0.f,0.f,0.f,0.f}, sB = sA, sC = sA, sD = sA;        \
      _Pragma("unroll")                                                      \
      for (int kk = 0; kk < 4; ++kk) {                                       \
        int r0 = l15, r1 = 16 + l15;                                         \
        bf16x8 k0f = *(const bf16x8*)(kb_ + (r0 << 8) +                      \
                     (((kk << 6) + (q16 << 4)) ^ ((r0 & 7) << 4)));          \
        bf16x8 k1f = *(const bf16x8*)(kb_ + (r1 << 8) +                      \
                     (((kk << 6) + (q16 << 4)) ^ ((r1 & 7) << 4)));          \
        sA = __builtin_amdgcn_mfma_f32_16x16x32_bf16(qf[kk], k0f, sA, 0, 0, 0); \
        sC = __builtin_amdgcn_mfma_f32_16x16x32_bf16(qg[kk], k0f, sC, 0, 0, 0); \
        sB = __builtin_amdgcn_mfma_f32_16x16x32_bf16(qf[kk], k1f, sB, 0, 0, 0); \
        sD = __builtin_amdgcn_mfma_f32_16x16x32_bf16(qg[kk], k1f, sD, 0, 0, 0); \
      }                                                                      \
      float pA[4], pB[4], pC[4], pD[4];                                      \
      if (s0_ + 32 <= t0) {                                                  \
        _Pragma("unroll")                                                    \
        for (int j = 0; j < 4; ++j) {                                        \
          pA[j] = __expf(sA[j]); pB[j] = __expf(sB[j]);                      \
          pC[j] = __expf(sC[j]); pD[j] = __expf(sD[j]);                      \
          ellA[j] += pA[j] + pB[j];                                          \
          ellB[j] += pC[j] + pD[j];                                          \
        }                                                                    \
      } else {                                                               \
        _Pragma("unroll")                                                    \
        for (int j = 0; j < 4; ++j) {                                        \
          int tA = t0 + rb + j, tB = tA + 16;                                \
          int sa = s0_ + l15;                                                \
          float vA_ = (sa <= tA)      ? sA[j] : 0.f;                         \
          float vB_ = (sa + 16 <= tA) ? sB[j] : 0.f;                         \
          float vC_ = (sa <= tB)      ? sC[j] : 0.f;                         \
          float vD_ = (sa + 16 <= tB) ? sD[j] : 0.f;                         \
          pA[j] = __expf(vA_); pB[j] = __expf(vB_);                          \
          pC[j] = __expf(vC_); pD[j] = __expf(vD_);                          \
          ellA[j] += pA[j] + pB[j];                                          \
          ellB[j] += pC[j] + pD[j];                                          \
        }                                                                    \
      }                                                                      \
      _Pragma("unroll")                                                      \
      for (int j = 0; j < 4; ++j) {                                          \
        int rA = rb + j;                                                     \
        int swzA = ((rA >> 1) & 3) << 4;                                     \
        *(unsigned short*)(Psm + (rA << 6) + ((l15 << 1) ^ swzA))        = f2bfru(pA[j]); \
        *(unsigned short*)(Psm + (rA << 6) + ((32 + (l15 << 1)) ^ swzA)) = f2bfru(pB[j]); \
        int rB = rA + 16;                                                    \
        int swzB = ((rB >> 1) & 3) << 4;                                     \
        *(unsigned short*)(Psm + (rB << 6) + ((l15 << 1) ^ swzB))        = f2bfru(pC[j]); \
        *(unsigned short*)(Psm + (rB << 6) + ((32 + (l15 << 1)) ^ swzB)) = f2bfru(pD[j]); \
      }                                                                      \
      asm volatile("s_waitcnt lgkmcnt(0)" ::: "memory");                     \
      bf16x8 paA, paB;                                                       \
      {                                                                      \
        int r = l15;                                                         \
        paA = *(const bf16x8*)(Psm + (r << 6) + ((q16 << 4) ^ (((r >> 1) & 3) << 4)));  \
        int r2 = 16 + l15;                                                   \
        paB = *(const bf16x8*)(Psm + (r2 << 6) + ((q16 << 4) ^ (((r2 >> 1) & 3) << 4))); \
      }                                                                      \
      _Pragma("unroll")                                                      \
      for (int ni = 0; ni < 8; ++ni) {                                       \
        oA[ni] = __builtin_amdgcn_mfma_f32_16x16x32_bf16(paA, VUSE[ni], oA[ni], 0, 0, 0); \
        oB[ni] = __builtin_amdgcn_mfma_f32_16x16x32_bf16(paB, VUSE[ni], oB[ni], 0, 0, 0); \
      }                                                                      \
    }                                                                        \
    if (hasNext_) {                                                          \
      if (hasStage_) asm volatile("s_waitcnt vmcnt(2)" ::: "memory");        \
      else           asm volatile("s_waitcnt vmcnt(0)" ::: "memory");        \
      __builtin_amdgcn_s_barrier();                                          \
    }                                                                        \
  } while (0)

  // prologue: K tiles 0,1 staged; V tile 0 loaded; drain; sync.
  STAGEK(0, smem);
  STAGEK(32, smem + 8192);
  LOADV(0, vA);
  asm volatile("s_waitcnt vmcnt(0)" ::: "memory");
  __syncthreads();

  int csl = 0;   // LDS slot of tile `it`
#pragma unroll 1
  for (int it = 0; it < numIter; it += 2) {
    int c1 = csl + 1; if (c1 >= 3) c1 -= 3;
    int c2 = csl + 2; if (c2 >= 3) c2 -= 3;
    char* sl0 = smem + (csl << 13);
    char* sl1 = smem + (c1 << 13);
    char* sl2 = smem + (c2 << 13);
    TILE(it,     sl0, sl2, vA, vB);
    TILE(it + 1, sl1, sl0, vB, vA);   // stage for it+3 reuses slot of it
    csl = c2;
  }

#undef TILE
#undef LOADV
#undef STAGEK

  // suffix correction: all s >= send have p == 1 exactly (both subtiles).
  const int send = t0 + 32;
  const float* sp = Suf + (size_t)(send >> 5) * 4096 + ((size_t)bh << 7);
  const float extra = (float)(2048 - send);
#pragma unroll
  for (int ni = 0; ni < 8; ++ni) {
    float sv = sp[(ni << 4) + l15];
#pragma unroll
    for (int j = 0; j < 4; ++j) { oA[ni][j] += sv; oB[ni][j] += sv; }
  }

  // deferred ell reductions, then normalize + store (both subtiles)
#pragma unroll
  for (int j = 0; j < 4; ++j) {
    float r = ellA[j];
    r += __shfl_xor(r, 1, 64);
    r += __shfl_xor(r, 2, 64);
    r += __shfl_xor(r, 4, 64);
    r += __shfl_xor(r, 8, 64);
    float inv = 1.0f / (r + extra);
    int t = t0 + rb + j;
    unsigned short* op = O + qkbase + (size_t)t * 2048;
#pragma unroll
    for (int ni = 0; ni < 8; ++ni)
      op[(ni << 4) + l15] = f2bf(oA[ni][j] * inv);

    float r2 = ellB[j];
    r2 += __shfl_xor(r2, 1, 64);
    r2 += __shfl_xor(r2, 2, 64);
    r2 += __shfl_xor(r2, 4, 64);
    r2 += __shfl_xor(r2, 8, 64);
    float inv2 = 1.0f / (r2 + extra);
    unsigned short* op2 = op + (size_t)16 * 2048;
#pragma unroll
    for (int ni = 0; ni < 8; ++ni)
      op2[(ni << 4) + l15] = f2bf(oB[ni][j] * inv2);
  }
}

// ---------------------------------------------------------------------------
// launch
// ---------------------------------------------------------------------------
extern "C" void kernel_launch(void* const* d_in, const int* in_sizes, int n_in,
                              void* d_out, int out_size, void* d_ws, size_t ws_size,
                              hipStream_t stream) {
  (void)in_sizes; (void)n_in; (void)out_size; (void)ws_size;
  const float* x  = (const float*)d_in[0];
  const float* Wq = (const float*)d_in[1];
  const float* Wk = (const float*)d_in[2];
  const float* Wv = (const float*)d_in[3];
  const float* Wo = (const float*)d_in[4];
  float* out = (float*)d_out;

  char* ws = (char*)d_ws;
  unsigned short* Xb  = (unsigned short*)(ws);                        // 16 MiB (reused as O)
  unsigned short* Wqt = (unsigned short*)(ws + 16777216);             // 8 MiB (reused as Suf)
  unsigned short* Wkt = (unsigned short*)(ws + 16777216 + 8388608);
  unsigned short* Wvt = (unsigned short*)(ws + 16777216 + 2 * 8388608);
  unsigned short* Wot = (unsigned short*)(ws + 16777216 + 3 * 8388608);
  unsigned short* Qb  = (unsigned short*)(ws + 50331648);             // 16 MiB
  unsigned short* Kb  = (unsigned short*)(ws + 67108864);             // 16 MiB
  unsigned short* Vt  = (unsigned short*)(ws + 83886080);             // 16 MiB
  unsigned short* Ob  = Xb;          // X dead after the QKV projection
  float*          Suf = (float*)Wqt; // W^T dead after the QKV projection

  {
    dim3 tb(32, 8), tg(64, 64, 5);
    prep_kernel<<<tg, tb, 0, stream>>>(x, Wq, Wk, Wv, Wo, Xb, Wqt, Wkt, Wvt, Wot);
  }
  // fused QKV projection: Bt = [Wqt|Wkt|Wvt] (contiguous), N=6144
  gemm_qkv<<<768, 512, 0, stream>>>(Xb, Wqt, Qb, Kb, Vt);

  vsuf_kernel<<<1024, 256, 0, stream>>>(Vt, Suf);

  attn_kernel<<<512, 256, 0, stream>>>(Qb, Kb, Vt, Suf, Ob);

  gemm_wo<<<512, 256, 0, stream>>>(Ob, Wot, out);
}

// Round 15
// 257.057 us; speedup vs baseline: 1.2044x; 1.2044x over previous
//
#include <hip/hip_runtime.h>

// ---------------------------------------------------------------------------
// MultiHeadAttention forward, MI355X/gfx950.
// B=2, T=2048, D=2048, H=16, Dh=128. fp32 in/out, bf16 MFMA internally.
// Reference quirks (faithful): multiplicative tril mask (masked scores = 0,
// NOT -inf -> exp(0)=1 contributions over ALL 2048 cols), scale = 1/sqrt(T).
// Round 15: REVERT round-14's V-from-global regression (uncoalesced + L1
// slower than LDS port). Base = round 13 (best). Micro-opt: K rows staged
// even/odd-interleaved so (pA,pB) score pairs are s-adjacent -> P-writes
// packed as 8 ds_write_b32 instead of 16 ds_write_b16 per lane.
// ---------------------------------------------------------------------------

typedef __attribute__((ext_vector_type(4))) float  f32x4;
typedef __attribute__((ext_vector_type(8))) short  bf16x8;
typedef __attribute__((ext_vector_type(4))) unsigned short u16x4;

#define AS1 __attribute__((address_space(1)))
#define AS3 __attribute__((address_space(3)))

__device__ __forceinline__ void llds16(const void* g, void* l) {
  __builtin_amdgcn_global_load_lds((const AS1 void*)g, (AS3 void*)l, 16, 0, 0);
}

__device__ __forceinline__ unsigned short f2bf(float f) {   // RNE
  unsigned int u = __builtin_bit_cast(unsigned int, f);
  u += 0x7fffu + ((u >> 16) & 1u);
  return (unsigned short)(u >> 16);
}

__device__ __forceinline__ unsigned short f2bfru(float f) { // round-half-up
  return (unsigned short)((__builtin_bit_cast(unsigned int, f) + 0x8000u) >> 16);
}

__device__ __forceinline__ float bf2f(unsigned short u) {
  return __builtin_bit_cast(float, (unsigned int)u << 16);
}

// ---------------------------------------------------------------------------
// Prep: z = 0..3 -> weight transpose (W [2048][2048] fp32 -> Wt[n][k] bf16),
//       z = 4    -> cast x (fp32 -> bf16), 8 elements/thread.
// ---------------------------------------------------------------------------
__global__ __launch_bounds__(256) void prep_kernel(
    const float* __restrict__ x,
    const float* __restrict__ W0, const float* __restrict__ W1,
    const float* __restrict__ W2, const float* __restrict__ W3,
    unsigned short* __restrict__ Xb,
    unsigned short* __restrict__ T0, unsigned short* __restrict__ T1,
    unsigned short* __restrict__ T2, unsigned short* __restrict__ T3) {
  __shared__ float tile[32][33];
  const int z = blockIdx.z;
  const int tx = threadIdx.x;       // 0..31
  const int ty = threadIdx.y;       // 0..7
  if (z == 4) {
    int blk = blockIdx.y * 64 + blockIdx.x;     // 0..4095
    int t = (ty << 5) + tx;                     // 0..255
    int i = blk * 512 + t;                      // f32x4 index; 4096*512 total
#pragma unroll
    for (int c = 0; c < 2; ++c) {
      f32x4 v = ((const f32x4*)x)[i + (c << 8)];
      u16x4 o;
      o[0] = f2bf(v[0]); o[1] = f2bf(v[1]); o[2] = f2bf(v[2]); o[3] = f2bf(v[3]);
      ((u16x4*)Xb)[i + (c << 8)] = o;
    }
    return;
  }
  const float* W = (z == 0) ? W0 : (z == 1) ? W1 : (z == 2) ? W2 : W3;
  unsigned short* Wt = (z == 0) ? T0 : (z == 1) ? T1 : (z == 2) ? T2 : T3;
  const int bx = blockIdx.x << 5;   // k base
  const int by = blockIdx.y << 5;   // n base
#pragma unroll
  for (int r = ty; r < 32; r += 8)
    tile[r][tx] = W[(size_t)(bx + r) * 2048 + by + tx];
  __syncthreads();
#pragma unroll
  for (int r = ty; r < 32; r += 8)
    Wt[(size_t)(by + r) * 2048 + bx + tx] = f2bf(tile[tx][r]);
}

// ---------------------------------------------------------------------------
// Fused QKV projection GEMM (round-8 best). Ring-3 depth-2 prefetch.
// C[M=4096][N=6144] = X[M][K=2048] @ Wt[N][K]^T, Wt = [Wq^T|Wk^T|Wv^T].
// BM=128, BN=256, BK=64. 8 waves (2M x 4N), wave tile 64x64 (4mi x 4ni).
// LDS: 3 slots x (A 16KB + B 32KB) = 144KB. Per K-tile: [vmcnt(6) ->
// s_barrier] ; stage(kt+2) ; 2 x { read 8 frags, 16 MFMA } free-running.
// Rows 128B = 8 chunks of 16B, chunk swizzle c ^= row&7 both sides.
// Grid 768 flat = 3 exact CU rounds; 3 bn panels per XCD (3MB -> L2).
// ---------------------------------------------------------------------------
__global__ __launch_bounds__(512, 2) void gemm_qkv(const unsigned short* __restrict__ A,
                                                   const unsigned short* __restrict__ Bt,
                                                   unsigned short* __restrict__ Qb,
                                                   unsigned short* __restrict__ Kb,
                                                   unsigned short* __restrict__ Vt) {
  constexpr int SLOT = 49152;                 // A 16384 + B 32768
  __shared__ __align__(16) char smem[3 * SLOT];
  const int tid  = threadIdx.x;
  const int lane = tid & 63;
  const int w    = tid >> 6;          // 0..7
  const int wr   = w >> 2;            // m-half (0..1)
  const int wc   = w & 3;             // n-quarter (0..3)
  const int q16  = lane >> 4;
  const int l15  = lane & 15;
  const int f    = blockIdx.x;
  const int g    = f >> 3;                        // 0..95
  const int bn   = (f & 7) * 3 + (g % 3);         // 0..23
  const int bm   = g / 3;                         // 0..31

  const int srow = tid >> 3;                      // 0..63
  const int scl  = (tid & 7) ^ (srow & 7);
  const unsigned short* aS = A  + (size_t)((bm << 7) + srow) * 2048 + (scl << 3);
  const unsigned short* bS = Bt + (size_t)(bn * 256 + srow) * 2048 + (scl << 3);
  const int sdst = tid << 4;

  // ds_read: row = base + l15, chunk = (ks*4 + q16) ^ (l15&7)
  const int swzb = (q16 ^ (l15 & 7)) << 4;        // ks=1: ^ 64
  const int aRd  = ((wr << 6) + l15) << 7;        // + mi*2048

  f32x4 acc[4][4];
#pragma unroll
  for (int i = 0; i < 4; ++i)
#pragma unroll
    for (int j = 0; j < 4; ++j) acc[i][j] = (f32x4){0.f, 0.f, 0.f, 0.f};

  auto stageT = [&](int kt, char* sb) {
    const size_t ko = (size_t)kt << 6;            // k element offset
    llds16(aS + ko,               sb + sdst);
    llds16(aS + (64 * 2048) + ko, sb + 8192 + sdst);
#pragma unroll
    for (int r = 0; r < 4; ++r)
      llds16(bS + (size_t)r * (64 * 2048) + ko, sb + 16384 + (r << 13) + sdst);
  };

  auto computeT = [&](const char* base) {
#pragma unroll
    for (int ks = 0; ks < 2; ++ks) {
      const int sw = swzb ^ (ks << 6);
      bf16x8 af[4], bf[4];
#pragma unroll
      for (int mi = 0; mi < 4; ++mi)
        af[mi] = *(const bf16x8*)(base + aRd + (mi << 11) + sw);
#pragma unroll
      for (int ni = 0; ni < 4; ++ni)
        bf[ni] = *(const bf16x8*)(base + 16384 + (((wc << 6) + l15) << 7) + (ni << 11) + sw);
      __builtin_amdgcn_s_setprio(1);
#pragma unroll
      for (int mi = 0; mi < 4; ++mi)
#pragma unroll
        for (int ni = 0; ni < 4; ++ni)
          acc[mi][ni] = __builtin_amdgcn_mfma_f32_16x16x32_bf16(af[mi], bf[ni], acc[mi][ni], 0, 0, 0);
      __builtin_amdgcn_s_setprio(0);
    }
  };

  char* s0 = smem;
  char* s1 = smem + SLOT;
  char* s2 = smem + 2 * SLOT;

#define W6()  asm volatile("s_waitcnt vmcnt(6)" ::: "memory")
#define W0()  asm volatile("s_waitcnt vmcnt(0)" ::: "memory")
#define BAR() __builtin_amdgcn_s_barrier()

  stageT(0, s0); stageT(1, s1);
  W6(); BAR();
  stageT(2, s2);
  computeT(s0);
#pragma unroll 1
  for (int b = 1; b <= 25; b += 3) {
    W6(); BAR(); stageT(b + 2, s0); computeT(s1);
    W6(); BAR(); stageT(b + 3, s1); computeT(s2);
    W6(); BAR(); stageT(b + 4, s2); computeT(s0);
  }
  W6(); BAR(); stageT(30, s0); computeT(s1);
  W6(); BAR(); stageT(31, s1); computeT(s2);
  W6(); BAR(); computeT(s0);
  W0(); BAR(); computeT(s1);

#undef W6
#undef W0
#undef BAR

  // epilogue. C/D layout: col = lane&15, row = (lane>>4)*4 + reg  [m89]
  const float qscale = 0.02209708691207961f;   // 1/sqrt(2048)
  const int rb = q16 << 2;
#pragma unroll
  for (int mi = 0; mi < 4; ++mi) {
    int m0 = (bm << 7) + (wr << 6) + (mi << 4) + rb;
#pragma unroll
    for (int ni = 0; ni < 4; ++ni) {
      int gn = (bn << 8) + (wc << 6) + (ni << 4) + l15;
      int region = gn >> 11;                     // 0 Q, 1 K, 2 V
      int nloc = gn & 2047;
      if (region == 0) {
#pragma unroll
        for (int j = 0; j < 4; ++j)
          Qb[(size_t)(m0 + j) * 2048 + nloc] = f2bf(acc[mi][ni][j] * qscale);
      } else if (region == 1) {
#pragma unroll
        for (int j = 0; j < 4; ++j)
          Kb[(size_t)(m0 + j) * 2048 + nloc] = f2bf(acc[mi][ni][j]);
      } else {
        u16x4 pk;
#pragma unroll
        for (int j = 0; j < 4; ++j) pk[j] = f2bf(acc[mi][ni][j]);
        int b = m0 >> 11, t = m0 & 2047;
        *(u16x4*)(Vt + ((size_t)((b << 4) + (nloc >> 7)) * 128 + (nloc & 127)) * 2048 + t) = pk;
      }
    }
  }
}

// ---------------------------------------------------------------------------
// Wo GEMM (passing): C fp32 = A[M][K] @ Bt[N][K]^T. BM=128, BN=128,
// wave tile 64x64 (2Mx2N), 4 waves, BK=32, ring-3 LDS, grid 512.
// ---------------------------------------------------------------------------
__global__ __launch_bounds__(256, 2) void gemm_wo(const unsigned short* __restrict__ A,
                                                  const unsigned short* __restrict__ Bt,
                                                  float* __restrict__ Co) {
  constexpr int SLOT = 8192 + 8192;
  __shared__ __align__(16) char smem[3 * SLOT];

  const int tid  = threadIdx.x;
  const int lane = tid & 63;
  const int w    = tid >> 6;                        // 0..3
  const int q16  = lane >> 4;
  const int l15  = lane & 15;
  const int f    = blockIdx.x;
  const int g    = f >> 3;
  const int bn   = ((f & 7) << 1) + (g & 1);
  const int bm   = g >> 1;
  const int wmb  = (w >> 1) << 6;
  const int wnb  = (w & 1) << 6;

  f32x4 acc[4][4];
#pragma unroll
  for (int i = 0; i < 4; ++i)
#pragma unroll
    for (int j = 0; j < 4; ++j) acc[i][j] = (f32x4){0.f, 0.f, 0.f, 0.f};

  const int rowA = tid >> 2;
  const int chA  = tid & 3;
  auto stageT = [&](int t, char* sb) {
    const int k0 = t << 5;
#pragma unroll
    for (int r = 0; r < 2; ++r) {
      int row = (r << 6) + rowA;
      const unsigned short* src = A + (size_t)((bm << 7) + row) * 2048 + k0
                                    + ((chA ^ ((row >> 1) & 3)) << 3);
      llds16(src, sb + (r << 12) + (w << 10));
    }
#pragma unroll
    for (int r = 0; r < 2; ++r) {
      int row = (r << 6) + rowA;
      const unsigned short* src = Bt + (size_t)((bn << 7) + row) * 2048 + k0
                                     + ((chA ^ ((row >> 1) & 3)) << 3);
      llds16(src, sb + 8192 + (r << 12) + (w << 10));
    }
  };

  auto computeT = [&](const char* base) {
    bf16x8 af[4], bf[4];
#pragma unroll
    for (int mi = 0; mi < 4; ++mi) {
      int row = wmb + (mi << 4) + l15;
      af[mi] = *(const bf16x8*)(base + (row << 6) + ((q16 ^ ((row >> 1) & 3)) << 4));
    }
#pragma unroll
    for (int ni = 0; ni < 4; ++ni) {
      int row = wnb + (ni << 4) + l15;
      bf[ni] = *(const bf16x8*)(base + 8192 + (row << 6) + ((q16 ^ ((row >> 1) & 3)) << 4));
    }
    __builtin_amdgcn_s_setprio(1);
#pragma unroll
    for (int mi = 0; mi < 4; ++mi)
#pragma unroll
      for (int ni = 0; ni < 4; ++ni)
        acc[mi][ni] = __builtin_amdgcn_mfma_f32_16x16x32_bf16(af[mi], bf[ni], acc[mi][ni], 0, 0, 0);
    __builtin_amdgcn_s_setprio(0);
  };

  auto STEP = [&](int t, char* cbase, char* sbase) {
    asm volatile("s_waitcnt vmcnt(4)" ::: "memory");
    __builtin_amdgcn_s_barrier();
    stageT(t + 2, sbase);
    computeT(cbase);
  };

  char* s0 = smem;
  char* s1 = smem + SLOT;
  char* s2 = smem + 2 * SLOT;

  stageT(0, s0); stageT(1, s1);
#pragma unroll 1
  for (int t = 0; t < 60; t += 3) {
    STEP(t,     s0, s2);
    STEP(t + 1, s1, s0);
    STEP(t + 2, s2, s1);
  }
  STEP(60, s0, s2);
  STEP(61, s1, s0);
  asm volatile("s_waitcnt vmcnt(4)" ::: "memory");
  __builtin_amdgcn_s_barrier();
  computeT(s2);
  asm volatile("s_waitcnt vmcnt(0)" ::: "memory");
  __builtin_amdgcn_s_barrier();
  computeT(s0);

  const int rb = q16 << 2;
#pragma unroll
  for (int mi = 0; mi < 4; ++mi) {
    int m0 = (bm << 7) + wmb + (mi << 4) + rb;
#pragma unroll
    for (int ni = 0; ni < 4; ++ni) {
      int n = (bn << 7) + wnb + (ni << 4) + l15;
#pragma unroll
      for (int j = 0; j < 4; ++j)
        Co[(size_t)(m0 + j) * 2048 + n] = acc[mi][ni][j];
    }
  }
}

// ---------------------------------------------------------------------------
// V suffix sums at 32-row granularity.
// Suf[j][bh][d] = sum_{s >= 32j} V[b, s, h, d],  j in 0..64 (Suf[64] = 0).
// ---------------------------------------------------------------------------
__global__ __launch_bounds__(256) void vsuf_kernel(const unsigned short* __restrict__ Vt,
                                                   float* __restrict__ Suf) {
  const int row  = blockIdx.x * 4 + (threadIdx.x >> 6);  // 0..4095
  const int lane = threadIdx.x & 63;
  const unsigned short* vp = Vt + (size_t)row * 2048 + (lane << 5);
  float a = 0.f;
#pragma unroll
  for (int c = 0; c < 4; ++c) {
    bf16x8 v = *(const bf16x8*)(vp + (c << 3));
#pragma unroll
    for (int j = 0; j < 8; ++j) a += bf2f((unsigned short)v[j]);
  }
  float I = a;
#pragma unroll
  for (int off = 1; off < 64; off <<= 1) {
    float t = __shfl_down(I, off, 64);
    I += (lane + off < 64) ? t : 0.f;
  }
  Suf[(size_t)lane * 4096 + row] = I;
  if (lane == 0) Suf[(size_t)64 * 4096 + row] = 0.f;
}

// ---------------------------------------------------------------------------
// Fused attention, QBLK=32/wave, ring-3 counted-vmcnt staging (round 13)
// + even/odd-interleaved K rows: LDS K row r holds global s = 2r (r<16) /
// 2r-31 (r>=16). sA's col l15 is then s=2*l15 and sB's is s=2*l15+1, so the
// per-lane (pA,pB) pair is s-adjacent -> P written as 8 ds_write_b32/lane
// (was 16 ds_write_b16). P fragment read stays a natural-order b128.
// Block = 4 waves x 32 q-rows = 128-row strip. Grid 512 = 32 bh x 16 strips.
// Decode: xcd = f&7, bh = xcd*4 + ((f>>3)&3);
// strip = (f>>5 < 8) ? 15-(f>>5) : (f>>5)-8  (complementary pairing).
// Q PRE-SCALED by 1/sqrt(T). Per 32-s tile: stage(it+2) -> compute(it) ->
// vmcnt(4) -> barrier; exact-count tail. Mask only on the straddling tile
// (s0 == t0); s >= t0+32 covered by V-suffix sums (p == 1 exactly).
// ---------------------------------------------------------------------------
__global__ __launch_bounds__(256, 2) void attn_kernel(const unsigned short* __restrict__ Q,
                                                      const unsigned short* __restrict__ K,
                                                      const unsigned short* __restrict__ V,  // Vt layout
                                                      const float* __restrict__ Suf,
                                                      unsigned short* __restrict__ O) {
  __shared__ __align__(16) char smem[57344];  // 3 slots x (K 8K | V 8K) | P 4x2K
  const int tid  = threadIdx.x;
  const int lane = tid & 63;
  const int w    = tid >> 6;
  const int q16  = lane >> 4;
  const int l15  = lane & 15;
  const int f    = blockIdx.x;
  const int bh   = ((f & 7) << 2) + ((f >> 3) & 3);
  const int fs   = f >> 5;                            // 0..15
  const int strip = (fs < 8) ? (15 - fs) : (fs - 8);  // complementary pairing
  const int b  = bh >> 4;
  const size_t qkbase = ((size_t)(b << 11)) * 2048 + ((size_t)(bh & 15) << 7);
  const size_t vbase  = (size_t)bh << 18;     // bh*128*2048
  const int rb = q16 << 2;
  char* Psm = smem + 49152 + (w << 11);       // 2KB per wave

  const int numIter = 4 * strip + 4;
  const int t0 = (strip << 7) + (w << 5);     // wave's 32-row base (mult of 32)

  auto stage = [&](int s0, int sb) {
#pragma unroll
    for (int c = 0; c < 2; ++c) {
      int ch = (w << 1) + c;
      int rowK = (ch << 2) + q16;                        // LDS row 0..31
      // even/odd interleave: LDS row r holds global s-row sigma(r)
      int srcK = (rowK < 16) ? (rowK << 1) : ((rowK << 1) - 31);
      int colbK = (l15 << 4) ^ ((rowK & 7) << 4);
      llds16(K + qkbase + (size_t)(s0 + srcK) * 2048 + (colbK >> 1), smem + sb + (ch << 10));
      int rowV = (ch << 4) + (lane >> 2);                // 16 rows / 1KB chunk
      int colbV = ((lane & 3) << 4) ^ (((rowV >> 2) & 3) << 4);
      llds16(V + vbase + (size_t)rowV * 2048 + s0 + (colbV >> 1), smem + sb + 8192 + (ch << 10));
    }
  };

  // Q fragments, both subtiles (rows t0.. and t0+16..)
  bf16x8 qf[4], qg[4];
  {
    const unsigned short* qp = Q + qkbase + (size_t)(t0 + l15) * 2048 + (q16 << 3);
#pragma unroll
    for (int kk = 0; kk < 4; ++kk) qf[kk] = *(const bf16x8*)(qp + (kk << 5));
    const unsigned short* qp2 = qp + (size_t)16 * 2048;
#pragma unroll
    for (int kk = 0; kk < 4; ++kk) qg[kk] = *(const bf16x8*)(qp2 + (kk << 5));
  }

  f32x4 oA[8], oB[8];
#pragma unroll
  for (int i = 0; i < 8; ++i) { oA[i] = (f32x4){0.f,0.f,0.f,0.f}; oB[i] = (f32x4){0.f,0.f,0.f,0.f}; }
  float ellA[4] = {0.f,0.f,0.f,0.f}, ellB[4] = {0.f,0.f,0.f,0.f};

  // prologue: tiles 0,1 staged; wait tile 0 (tile 1's 4 loads in flight)
  stage(0, 0);
  stage(32, 16384);
  asm volatile("s_waitcnt vmcnt(4)" ::: "memory");
  __syncthreads();

  int cs = 0;   // slot of tile `it`
  for (int it = 0; it < numIter; ++it) {
    const int s0 = it << 5;
    const bool st = (it + 2 < numIter);
    if (st) {
      int ss = cs + 2; if (ss >= 3) ss -= 3;
      stage(s0 + 64, ss << 14);
    }

    if (s0 <= t0) {   // tile not entirely above this wave's 32 rows
      const int kb = cs << 14;
      const int vb = kb + 8192;

      // QK^T: K-frags shared by both q-subtiles (16 MFMA).
      // sA col l15 -> s = 2*l15; sB col l15 -> s = 2*l15+1 (interleaved K).
      f32x4 sA = (f32x4){0.f,0.f,0.f,0.f}, sB = sA, sC = sA, sD = sA;
#pragma unroll
      for (int kk = 0; kk < 4; ++kk) {
        int r0 = l15, r1 = 16 + l15;
        bf16x8 k0f = *(const bf16x8*)(smem + kb + (r0 << 8) + (((kk << 6) + (q16 << 4)) ^ ((r0 & 7) << 4)));
        bf16x8 k1f = *(const bf16x8*)(smem + kb + (r1 << 8) + (((kk << 6) + (q16 << 4)) ^ ((r1 & 7) << 4)));
        sA = __builtin_amdgcn_mfma_f32_16x16x32_bf16(qf[kk], k0f, sA, 0, 0, 0);
        sC = __builtin_amdgcn_mfma_f32_16x16x32_bf16(qg[kk], k0f, sC, 0, 0, 0);
        sB = __builtin_amdgcn_mfma_f32_16x16x32_bf16(qf[kk], k1f, sB, 0, 0, 0);
        sD = __builtin_amdgcn_mfma_f32_16x16x32_bf16(qg[kk], k1f, sD, 0, 0, 0);
      }

      float pA[4], pB[4], pC[4], pD[4];
      if (s0 + 32 <= t0) {           // fully unmasked tile (common case)
#pragma unroll
        for (int j = 0; j < 4; ++j) {
          pA[j] = __expf(sA[j]); pB[j] = __expf(sB[j]);
          pC[j] = __expf(sC[j]); pD[j] = __expf(sD[j]);
          ellA[j] += pA[j] + pB[j];
          ellB[j] += pC[j] + pD[j];
        }
      } else {                       // straddling tile (s0 == t0): mask -> exp(0)=1
#pragma unroll
        for (int j = 0; j < 4; ++j) {
          int tA = t0 + rb + j, tB = tA + 16;
          int sa = s0 + (l15 << 1);           // sA's actual s; sB's is sa+1
          float vA = (sa <= tA)     ? sA[j] : 0.f;
          float vB = (sa + 1 <= tA) ? sB[j] : 0.f;
          float vC = (sa <= tB)     ? sC[j] : 0.f;
          float vD = (sa + 1 <= tB) ? sD[j] : 0.f;
          pA[j] = __expf(vA); pB[j] = __expf(vB);
          pC[j] = __expf(vC); pD[j] = __expf(vD);
          ellA[j] += pA[j] + pB[j];
          ellB[j] += pC[j] + pD[j];
        }
      }

      // P -> per-wave LDS [32 t][32 s] bf16, swz: byte col ^= ((row>>1)&3)<<4.
      // (pA,pB) pair = s cols (2*l15, 2*l15+1) -> one b32 at byte 4*l15.
#pragma unroll
      for (int j = 0; j < 4; ++j) {
        int rA = rb + j;
        int swzA = ((rA >> 1) & 3) << 4;
        unsigned int pk0 = (unsigned int)f2bfru(pA[j]) | ((unsigned int)f2bfru(pB[j]) << 16);
        *(unsigned int*)(Psm + (rA << 6) + ((l15 << 2) ^ swzA)) = pk0;
        int rB = rA + 16;
        int swzB = ((rB >> 1) & 3) << 4;
        unsigned int pk1 = (unsigned int)f2bfru(pC[j]) | ((unsigned int)f2bfru(pD[j]) << 16);
        *(unsigned int*)(Psm + (rB << 6) + ((l15 << 2) ^ swzB)) = pk1;
      }
      asm volatile("s_waitcnt lgkmcnt(0)" ::: "memory");

      bf16x8 paA, paB;
      {
        int r = l15;
        paA = *(const bf16x8*)(Psm + (r << 6) + ((q16 << 4) ^ (((r >> 1) & 3) << 4)));
        int r2 = 16 + l15;
        paB = *(const bf16x8*)(Psm + (r2 << 6) + ((q16 << 4) ^ (((r2 >> 1) & 3) << 4)));
      }
      // PV: V-frags shared by both q-subtiles (16 MFMA); natural s order.
#pragma unroll
      for (int ni = 0; ni < 8; ++ni) {
        int dr = (ni << 4) + l15;
        bf16x8 vbf = *(const bf16x8*)(smem + vb + (dr << 6) + ((q16 << 4) ^ (((dr >> 2) & 3) << 4)));
        oA[ni] = __builtin_amdgcn_mfma_f32_16x16x32_bf16(paA, vbf, oA[ni], 0, 0, 0);
        oB[ni] = __builtin_amdgcn_mfma_f32_16x16x32_bf16(paB, vbf, oB[ni], 0, 0, 0);
      }
    }

    if (it + 1 < numIter) {
      if (st) asm volatile("s_waitcnt vmcnt(4)" ::: "memory");  // tile it+1 landed
      else    asm volatile("s_waitcnt vmcnt(0)" ::: "memory");  // tail: <=4 outstanding
      __builtin_amdgcn_s_barrier();
    }
    cs = (cs + 1 == 3) ? 0 : cs + 1;
  }

  // suffix correction: all s >= send have p == 1 exactly (both subtiles).
  const int send = t0 + 32;
  const float* sp = Suf + (size_t)(send >> 5) * 4096 + ((size_t)bh << 7);
  const float extra = (float)(2048 - send);
#pragma unroll
  for (int ni = 0; ni < 8; ++ni) {
    float sv = sp[(ni << 4) + l15];
#pragma unroll
    for (int j = 0; j < 4; ++j) { oA[ni][j] += sv; oB[ni][j] += sv; }
  }

  // deferred ell reductions, then normalize + store (both subtiles)
#pragma unroll
  for (int j = 0; j < 4; ++j) {
    float r = ellA[j];
    r += __shfl_xor(r, 1, 64);
    r += __shfl_xor(r, 2, 64);
    r += __shfl_xor(r, 4, 64);
    r += __shfl_xor(r, 8, 64);
    float inv = 1.0f / (r + extra);
    int t = t0 + rb + j;
    unsigned short* op = O + qkbase + (size_t)t * 2048;
#pragma unroll
    for (int ni = 0; ni < 8; ++ni)
      op[(ni << 4) + l15] = f2bf(oA[ni][j] * inv);

    float r2 = ellB[j];
    r2 += __shfl_xor(r2, 1, 64);
    r2 += __shfl_xor(r2, 2, 64);
    r2 += __shfl_xor(r2, 4, 64);
    r2 += __shfl_xor(r2, 8, 64);
    float inv2 = 1.0f / (r2 + extra);
    unsigned short* op2 = op + (size_t)16 * 2048;
#pragma unroll
    for (int ni = 0; ni < 8; ++ni)
      op2[(ni << 4) + l15] = f2bf(oB[ni][j] * inv2);
  }
}

// ---------------------------------------------------------------------------
// launch
// ---------------------------------------------------------------------------
extern "C" void kernel_launch(void* const* d_in, const int* in_sizes, int n_in,
                              void* d_out, int out_size, void* d_ws, size_t ws_size,
                              hipStream_t stream) {
  (void)in_sizes; (void)n_in; (void)out_size; (void)ws_size;
  const float* x  = (const float*)d_in[0];
  const float* Wq = (const float*)d_in[1];
  const float* Wk = (const float*)d_in[2];
  const float* Wv = (const float*)d_in[3];
  const float* Wo = (const float*)d_in[4];
  float* out = (float*)d_out;

  char* ws = (char*)d_ws;
  unsigned short* Xb  = (unsigned short*)(ws);                        // 16 MiB (reused as O)
  unsigned short* Wqt = (unsigned short*)(ws + 16777216);             // 8 MiB (reused as Suf)
  unsigned short* Wkt = (unsigned short*)(ws + 16777216 + 8388608);
  unsigned short* Wvt = (unsigned short*)(ws + 16777216 + 2 * 8388608);
  unsigned short* Wot = (unsigned short*)(ws + 16777216 + 3 * 8388608);
  unsigned short* Qb  = (unsigned short*)(ws + 50331648);             // 16 MiB
  unsigned short* Kb  = (unsigned short*)(ws + 67108864);             // 16 MiB
  unsigned short* Vt  = (unsigned short*)(ws + 83886080);             // 16 MiB
  unsigned short* Ob  = Xb;          // X dead after the QKV projection
  float*          Suf = (float*)Wqt; // W^T dead after the QKV projection

  {
    dim3 tb(32, 8), tg(64, 64, 5);
    prep_kernel<<<tg, tb, 0, stream>>>(x, Wq, Wk, Wv, Wo, Xb, Wqt, Wkt, Wvt, Wot);
  }
  // fused QKV projection: Bt = [Wqt|Wkt|Wvt] (contiguous), N=6144
  gemm_qkv<<<768, 512, 0, stream>>>(Xb, Wqt, Qb, Kb, Vt);

  vsuf_kernel<<<1024, 256, 0, stream>>>(Vt, Suf);

  attn_kernel<<<512, 256, 0, stream>>>(Qb, Kb, Vt, Suf, Ob);

  gemm_wo<<<512, 256, 0, stream>>>(Ob, Wot, out);
}